// Round 2
// baseline (202.414 us; speedup 1.0000x reference)
//
#include <hip/hip_runtime.h>
#include <math.h>

#define BATCH 512
#define DIM   1024
#define NCLUS 16384
#define TINV  20.0f   // 1/TEMP

typedef __attribute__((ext_vector_type(4))) float f32x4;
typedef __attribute__((ext_vector_type(8))) short bf16x8;

static __device__ __forceinline__ unsigned short f2bf(float f) {
  unsigned int u = __float_as_uint(f);
  u += 0x7FFFu + ((u >> 16) & 1u);   // round-to-nearest-even
  return (unsigned short)(u >> 16);
}

// ---------------------------------------------------------------------------
// Kernel 1: row L2-normalize (both modalities), emit f32 + bf16 copies of x.
// Also zeroes the 2048-float accumulator region (rowsum + tgtlog).
// grid: 1024 blocks (512 rgb, 512 ir) x 256 threads
// ---------------------------------------------------------------------------
__global__ void nrm_kernel(const float* __restrict__ in_rgb,
                           const float* __restrict__ in_ir,
                           float* __restrict__ xf,            // [2][512][1024]
                           unsigned short* __restrict__ xb,   // [2][512][1024]
                           float* __restrict__ accum) {       // 2048 floats
  int gid = blockIdx.x * blockDim.x + threadIdx.x;
  if (gid < 2048) accum[gid] = 0.0f;

  int row = blockIdx.x;
  int mod = row >> 9;
  int r   = row & 511;
  const float* in = (mod ? in_ir : in_rgb) + (size_t)r * DIM;
  float* xo          = xf + ((size_t)mod * BATCH + r) * DIM;
  unsigned short* xbo = xb + ((size_t)mod * BATCH + r) * DIM;

  int t = threadIdx.x;
  float4 v = ((const float4*)in)[t];
  float ss = v.x*v.x + v.y*v.y + v.z*v.z + v.w*v.w;
#pragma unroll
  for (int m = 1; m < 64; m <<= 1) ss += __shfl_xor(ss, m, 64);
  __shared__ float red[4];
  if ((t & 63) == 0) red[t >> 6] = ss;
  __syncthreads();
  float inv = 1.0f / fmaxf(sqrtf(red[0] + red[1] + red[2] + red[3]), 1e-12f);
  float4 o = make_float4(v.x * inv, v.y * inv, v.z * inv, v.w * inv);
  ((float4*)xo)[t] = o;
  ushort4 ob = make_ushort4(f2bf(o.x), f2bf(o.y), f2bf(o.z), f2bf(o.w));
  ((ushort4*)xbo)[t] = ob;
}

// ---------------------------------------------------------------------------
// Kernel 2: bf16 MFMA GEMM  logits = (x @ F^T) * 20, folded into
//   rowsum[b] += sum_n exp(logit), tgtlog[b] = logit at n == target[b].
// Tile 128(batch) x 128(n), BK=32, 4 waves each computing 64x64.
// grid: (512, 2) blocks x 256 threads.  blockIdx.x = nt*4 + bt.
// ---------------------------------------------------------------------------
#define BM 128
#define BN 128
#define BK 32
#define LDP 40   // padded LDS stride (bf16 elems): 80B rows

__global__ void gemm_lse_kernel(const unsigned short* __restrict__ xb,  // [2][512][1024]
                                const float* __restrict__ f_rgb,
                                const float* __restrict__ f_ir,
                                const int* __restrict__ t_rgb,
                                const int* __restrict__ t_ir,
                                float* __restrict__ rowsum,   // [2][512]
                                float* __restrict__ tgtlog) { // [2][512]
  const int mod = blockIdx.y;
  const unsigned short* X = xb + (size_t)mod * BATCH * DIM;
  const float* F  = mod ? f_ir : f_rgb;
  const int*   tg = mod ? t_ir : t_rgb;
  float* rs = rowsum + mod * BATCH;
  float* tl = tgtlog + mod * BATCH;

  const int nt = blockIdx.x >> 2;
  const int bt = blockIdx.x & 3;

  __shared__ unsigned short As[BM][LDP];
  __shared__ unsigned short Bs[BN][LDP];

  const int tid  = threadIdx.x;
  const int wid  = tid >> 6;
  const int lane = tid & 63;
  const int wr = wid >> 1, wc = wid & 1;
  const int l15 = lane & 15, lhi = lane >> 4;

  f32x4 acc[4][4];
#pragma unroll
  for (int m = 0; m < 4; ++m)
#pragma unroll
    for (int n = 0; n < 4; ++n) acc[m][n] = (f32x4){0.f, 0.f, 0.f, 0.f};

  for (int kk = 0; kk < DIM; kk += BK) {
    // stage A tile: 128 rows x 32 cols bf16; 8 elems (16B) per thread,
    // 4 loads per row -> row = id>>2, col = (id&3)*8
#pragma unroll
    for (int i = 0; i < 2; ++i) {
      int id = tid + i * 256;            // 0..511
      int row = id >> 2, c8 = (id & 3) << 3;
      uint4 v = *(const uint4*)(X + (size_t)(bt * BM + row) * DIM + kk + c8);
      *(uint4*)(&As[row][c8]) = v;
    }
    // stage B tile: 128 rows x 32 cols f32 -> bf16; 4 elems per thread,
    // 8 loads per row -> row = id>>3, col = (id&7)*4
#pragma unroll
    for (int i = 0; i < 4; ++i) {
      int id = tid + i * 256;            // 0..1023
      int row = id >> 3, c4 = (id & 7) << 2;
      float4 v = *(const float4*)(F + (size_t)(nt * BN + row) * DIM + kk + c4);
      ushort4 b = make_ushort4(f2bf(v.x), f2bf(v.y), f2bf(v.z), f2bf(v.w));
      *(ushort4*)(&Bs[row][c4]) = b;
    }
    __syncthreads();

    bf16x8 a[4], b[4];
#pragma unroll
    for (int m = 0; m < 4; ++m)
      a[m] = *(const bf16x8*)(&As[wr * 64 + m * 16 + l15][lhi * 8]);
#pragma unroll
    for (int n = 0; n < 4; ++n)
      b[n] = *(const bf16x8*)(&Bs[wc * 64 + n * 16 + l15][lhi * 8]);
#pragma unroll
    for (int m = 0; m < 4; ++m)
#pragma unroll
      for (int n = 0; n < 4; ++n)
        acc[m][n] = __builtin_amdgcn_mfma_f32_16x16x32_bf16(a[m], b[n], acc[m][n], 0, 0, 0);
    __syncthreads();
  }

  // epilogue: exp-sum reduce over the 128 columns of this tile + target capture
#pragma unroll
  for (int m = 0; m < 4; ++m) {
    const int browbase = bt * BM + wr * 64 + m * 16 + lhi * 4;
    float esum[4];
#pragma unroll
    for (int j = 0; j < 4; ++j) {
      const int brow = browbase + j;
      const int t = tg[brow];
      float e = 0.f;
#pragma unroll
      for (int n = 0; n < 4; ++n) {
        float logit = acc[m][n][j] * TINV;
        e += __expf(logit);
        int col = nt * BN + wc * 64 + n * 16 + l15;
        if (col == t) tl[brow] = logit;
      }
      esum[j] = e;
    }
#pragma unroll
    for (int j = 0; j < 4; ++j) {
      float e = esum[j];
      e += __shfl_xor(e, 1, 64);
      e += __shfl_xor(e, 2, 64);
      e += __shfl_xor(e, 4, 64);
      e += __shfl_xor(e, 8, 64);
      if (l15 == 0) atomicAdd(rs + browbase + j, e);
    }
  }
}

// ---------------------------------------------------------------------------
// Kernel 3: copy both feature banks into d_out (+2 float offset -> float2 ops)
// ---------------------------------------------------------------------------
__global__ void copy_kernel(const float* __restrict__ f_rgb,
                            const float* __restrict__ f_ir,
                            float* __restrict__ out) {  // out + 2 base
  const size_t n2 = (size_t)NCLUS * DIM / 2;   // float2 per modality
  size_t stride = (size_t)gridDim.x * blockDim.x;
  for (size_t i = (size_t)blockIdx.x * blockDim.x + threadIdx.x; i < 2 * n2; i += stride) {
    float2 v = (i < n2) ? ((const float2*)f_rgb)[i] : ((const float2*)f_ir)[i - n2];
    ((float2*)out)[i] = v;
  }
}

// ---------------------------------------------------------------------------
// Kernel 4: loss = mean(log(rowsum) - tgtlog) per modality
// ---------------------------------------------------------------------------
__global__ void loss_kernel(const float* __restrict__ rowsum,
                            const float* __restrict__ tgtlog,
                            float* __restrict__ out) {
  int t = threadIdx.x;  // 512
  float lr = logf(rowsum[t]) - tgtlog[t];
  float li = logf(rowsum[BATCH + t]) - tgtlog[BATCH + t];
#pragma unroll
  for (int m = 1; m < 64; m <<= 1) { lr += __shfl_xor(lr, m, 64); li += __shfl_xor(li, m, 64); }
  __shared__ float sr[8], si[8];
  if ((t & 63) == 0) { sr[t >> 6] = lr; si[t >> 6] = li; }
  __syncthreads();
  if (t == 0) {
    float a = 0.f, b = 0.f;
#pragma unroll
    for (int i = 0; i < 8; ++i) { a += sr[i]; b += si[i]; }
    out[0] = a * (1.0f / BATCH);
    out[1] = b * (1.0f / BATCH);
  }
}

// ---------------------------------------------------------------------------
// Kernel 5: sequential momentum update chains on the copied banks.
// One block per (sample, modality); only the first occurrence of a target
// processes its whole duplicate chain in sample order.
// ---------------------------------------------------------------------------
__global__ void mom_kernel(const int* __restrict__ t_rgb,
                           const int* __restrict__ t_ir,
                           const float* __restrict__ xf,   // [2][512][1024]
                           float* __restrict__ out) {      // out + 2 base
  const int i   = blockIdx.x;
  const int mod = blockIdx.y;
  const int* tg = mod ? t_ir : t_rgb;
  const int y = tg[i];
  for (int j = 0; j < i; ++j)
    if (tg[j] == y) return;          // uniform: another block owns this chain

  const float* x = xf + (size_t)mod * BATCH * DIM;
  float* rowp = out + (size_t)mod * NCLUS * DIM + (size_t)y * DIM;

  const int t = threadIdx.x;  // 256
  float2 r0 = ((const float2*)rowp)[t];
  float2 r1 = ((const float2*)rowp)[t + 256];
  __shared__ float red[4];

  for (int j = i; j < BATCH; ++j) {
    if (tg[j] != y) continue;        // uniform
    const float2* xr = (const float2*)(x + (size_t)j * DIM);
    float2 x0 = xr[t], x1 = xr[t + 256];
    r0.x = 0.9f * r0.x + 0.1f * x0.x;
    r0.y = 0.9f * r0.y + 0.1f * x0.y;
    r1.x = 0.9f * r1.x + 0.1f * x1.x;
    r1.y = 0.9f * r1.y + 0.1f * x1.y;
    float ss = r0.x*r0.x + r0.y*r0.y + r1.x*r1.x + r1.y*r1.y;
#pragma unroll
    for (int m = 1; m < 64; m <<= 1) ss += __shfl_xor(ss, m, 64);
    if ((t & 63) == 0) red[t >> 6] = ss;
    __syncthreads();
    float tot = red[0] + red[1] + red[2] + red[3];
    __syncthreads();
    float inv = 1.0f / sqrtf(tot);
    r0.x *= inv; r0.y *= inv; r1.x *= inv; r1.y *= inv;
  }
  ((float2*)rowp)[t] = r0;
  ((float2*)rowp)[t + 256] = r1;
}

// ---------------------------------------------------------------------------
extern "C" void kernel_launch(void* const* d_in, const int* in_sizes, int n_in,
                              void* d_out, int out_size, void* d_ws, size_t ws_size,
                              hipStream_t stream) {
  (void)in_sizes; (void)n_in; (void)out_size; (void)ws_size;
  const float* in_rgb = (const float*)d_in[0];
  const float* in_ir  = (const float*)d_in[1];
  const int*   t_rgb  = (const int*)d_in[2];
  const int*   t_ir   = (const int*)d_in[3];
  const float* f_rgb  = (const float*)d_in[4];
  const float* f_ir   = (const float*)d_in[5];
  float* out = (float*)d_out;

  char* ws = (char*)d_ws;
  float*          xf     = (float*)ws;                          // 4 MB  [2][512][1024] f32
  unsigned short* xb     = (unsigned short*)(ws + 4194304);     // 2 MB  [2][512][1024] bf16
  float*          rowsum = (float*)(ws + 6291456);              // 2048 f32 (rowsum+tgtlog)
  float*          tgtlog = rowsum + 1024;

  nrm_kernel<<<1024, 256, 0, stream>>>(in_rgb, in_ir, xf, xb, rowsum);
  gemm_lse_kernel<<<dim3(512, 2), 256, 0, stream>>>(xb, f_rgb, f_ir, t_rgb, t_ir, rowsum, tgtlog);
  copy_kernel<<<8192, 256, 0, stream>>>(f_rgb, f_ir, out + 2);
  loss_kernel<<<1, 512, 0, stream>>>(rowsum, tgtlog, out);
  mom_kernel<<<dim3(512, 2), 256, 0, stream>>>(t_rgb, t_ir, xf, out + 2);
}

// Round 3
// 189.547 us; speedup vs baseline: 1.0679x; 1.0679x over previous
//
#include <hip/hip_runtime.h>
#include <math.h>

#define BATCH 512
#define DIM   1024
#define NCLUS 16384
#define TINV  20.0f   // 1/TEMP

typedef __attribute__((ext_vector_type(4))) float f32x4;
typedef __attribute__((ext_vector_type(8))) short bf16x8;

static __device__ __forceinline__ unsigned short f2bf(float f) {
  unsigned int u = __float_as_uint(f);
  u += 0x7FFFu + ((u >> 16) & 1u);   // round-to-nearest-even
  return (unsigned short)(u >> 16);
}

typedef const __attribute__((address_space(1))) unsigned int* gas1_t;
typedef __attribute__((address_space(3))) unsigned int* las3_t;
// async global->LDS, 16B per lane; LDS dest = wave-uniform base + lane*16
static __device__ __forceinline__ void gload16(const void* g, void* l) {
  __builtin_amdgcn_global_load_lds((gas1_t)g, (las3_t)l, 16, 0, 0);
}

// ---------------------------------------------------------------------------
// Kernel 1: row L2-normalize (both modalities), emit f32 + bf16 copies of x.
// Also zeroes the 2048-float accumulator region (rowsum + tgtlog).
// ---------------------------------------------------------------------------
__global__ void nrm_kernel(const float* __restrict__ in_rgb,
                           const float* __restrict__ in_ir,
                           float* __restrict__ xf,            // [2][512][1024]
                           unsigned short* __restrict__ xb,   // [2][512][1024]
                           float* __restrict__ accum) {       // 2048 floats
  int gid = blockIdx.x * blockDim.x + threadIdx.x;
  if (gid < 2048) accum[gid] = 0.0f;

  int row = blockIdx.x;
  int mod = row >> 9;
  int r   = row & 511;
  const float* in = (mod ? in_ir : in_rgb) + (size_t)r * DIM;
  float* xo          = xf + ((size_t)mod * BATCH + r) * DIM;
  unsigned short* xbo = xb + ((size_t)mod * BATCH + r) * DIM;

  int t = threadIdx.x;
  float4 v = ((const float4*)in)[t];
  float ss = v.x*v.x + v.y*v.y + v.z*v.z + v.w*v.w;
#pragma unroll
  for (int m = 1; m < 64; m <<= 1) ss += __shfl_xor(ss, m, 64);
  __shared__ float red[4];
  if ((t & 63) == 0) red[t >> 6] = ss;
  __syncthreads();
  float inv = 1.0f / fmaxf(sqrtf(red[0] + red[1] + red[2] + red[3]), 1e-12f);
  float4 o = make_float4(v.x * inv, v.y * inv, v.z * inv, v.w * inv);
  ((float4*)xo)[t] = o;
  ushort4 ob = make_ushort4(f2bf(o.x), f2bf(o.y), f2bf(o.z), f2bf(o.w));
  ((ushort4*)xbo)[t] = ob;
}

// ---------------------------------------------------------------------------
// Kernel 2: bank copy to d_out (f32 exact) + fused bf16 conversion of F.
// out is only 8B-aligned (d_out+2 floats) -> float2 stores there.
// ---------------------------------------------------------------------------
__global__ void cvtcopy_kernel(const float* __restrict__ f_rgb,
                               const float* __restrict__ f_ir,
                               float* __restrict__ out,           // out + 2
                               unsigned short* __restrict__ fb,   // [2][16384][1024] bf16
                               int precvt) {
  const size_t n4 = (size_t)NCLUS * DIM / 4;   // float4 per bank
  size_t stride = (size_t)gridDim.x * blockDim.x;
  for (size_t i = (size_t)blockIdx.x * blockDim.x + threadIdx.x; i < 2 * n4; i += stride) {
    const float4 v = (i < n4) ? ((const float4*)f_rgb)[i] : ((const float4*)f_ir)[i - n4];
    float2* o2 = (float2*)(out + 4 * i);
    o2[0] = make_float2(v.x, v.y);
    o2[1] = make_float2(v.z, v.w);
    if (precvt)
      ((ushort4*)fb)[i] = make_ushort4(f2bf(v.x), f2bf(v.y), f2bf(v.z), f2bf(v.w));
  }
}

// ---------------------------------------------------------------------------
// Kernel 3: bf16 MFMA GEMM (m97 structure) + fused exp-sum / target capture.
// Tile 128x128, BK=32, 4 waves (2x2) each 64x64. Linear LDS [128][32],
// staged via global_load_lds dwordx4. grid: (128 nt, 8 = mod*4+bt) so the
// linear dispatch index mod 8 == nt mod 8 -> all blocks sharing an F panel
// land on one XCD (L2 reuse).
// ---------------------------------------------------------------------------
#define BM 128
#define BN 128
#define BK 32

template<int PRECVT>
__global__ void gemm_lse_kernel(const unsigned short* __restrict__ xb,
                                const unsigned short* __restrict__ fb,
                                const float* __restrict__ f_rgb,
                                const float* __restrict__ f_ir,
                                const int* __restrict__ t_rgb,
                                const int* __restrict__ t_ir,
                                float* __restrict__ rowsum,   // [2][512]
                                float* __restrict__ tgtlog) { // [2][512]
  const int nt  = blockIdx.x;        // 0..127
  const int bt  = blockIdx.y & 3;    // batch tile
  const int mod = blockIdx.y >> 2;   // modality

  const unsigned short* X  = xb + ((size_t)mod * BATCH + bt * BM) * DIM;
  const unsigned short* Bb = fb + ((size_t)mod * NCLUS + nt * BN) * DIM;
  const float* Ff = (mod ? f_ir : f_rgb) + (size_t)nt * BN * DIM;
  const int*   tg = mod ? t_ir : t_rgb;
  float* rs = rowsum + mod * BATCH;
  float* tl = tgtlog + mod * BATCH;

  __shared__ __align__(16) unsigned short As[BM * BK];
  __shared__ __align__(16) unsigned short Bs[BN * BK];

  const int tid  = threadIdx.x;
  const int wid  = tid >> 6;
  const int lane = tid & 63;
  const int wr = wid >> 1, wc = wid & 1;
  const int l15 = lane & 15, lhi = lane >> 4;

  f32x4 acc[4][4];
#pragma unroll
  for (int m = 0; m < 4; ++m)
#pragma unroll
    for (int n = 0; n < 4; ++n) acc[m][n] = (f32x4){0.f, 0.f, 0.f, 0.f};

  for (int kk = 0; kk < DIM; kk += BK) {
    // stage A (and B if pre-converted): chunk q = i*256+tid -> LDS byte q*16
#pragma unroll
    for (int i = 0; i < 2; ++i) {
      int q = i * 256 + tid;           // 0..511
      gload16(X + (size_t)(q >> 2) * DIM + kk + (q & 3) * 8,
              As + (size_t)(i * 256 + wid * 64) * 8);
      if (PRECVT)
        gload16(Bb + (size_t)(q >> 2) * DIM + kk + (q & 3) * 8,
                Bs + (size_t)(i * 256 + wid * 64) * 8);
    }
    if (!PRECVT) {
#pragma unroll
      for (int i = 0; i < 4; ++i) {
        int id = i * 256 + tid;        // 0..1023
        int row = id >> 3, c4 = (id & 7) << 2;
        float4 v = *(const float4*)(Ff + (size_t)row * DIM + kk + c4);
        *(ushort4*)(&Bs[row * BK + c4]) =
            make_ushort4(f2bf(v.x), f2bf(v.y), f2bf(v.z), f2bf(v.w));
      }
    }
    __syncthreads();

    bf16x8 a[4], b[4];
#pragma unroll
    for (int m = 0; m < 4; ++m)
      a[m] = *(const bf16x8*)(&As[(wr * 64 + m * 16 + l15) * BK + lhi * 8]);
#pragma unroll
    for (int n = 0; n < 4; ++n)
      b[n] = *(const bf16x8*)(&Bs[(wc * 64 + n * 16 + l15) * BK + lhi * 8]);
#pragma unroll
    for (int m = 0; m < 4; ++m)
#pragma unroll
      for (int n = 0; n < 4; ++n)
        acc[m][n] = __builtin_amdgcn_mfma_f32_16x16x32_bf16(a[m], b[n], acc[m][n], 0, 0, 0);
    __syncthreads();
  }

  // epilogue: exp-sum reduce over this tile's 128 columns + target capture
#pragma unroll
  for (int m = 0; m < 4; ++m) {
    const int browbase = bt * BM + wr * 64 + m * 16 + lhi * 4;
    float esum[4];
#pragma unroll
    for (int j = 0; j < 4; ++j) {
      const int brow = browbase + j;
      const int t = tg[brow];
      float e = 0.f;
#pragma unroll
      for (int n = 0; n < 4; ++n) {
        float logit = acc[m][n][j] * TINV;
        e += __expf(logit);
        int col = nt * BN + wc * 64 + n * 16 + l15;
        if (col == t) tl[brow] = logit;
      }
      esum[j] = e;
    }
#pragma unroll
    for (int j = 0; j < 4; ++j) {
      float e = esum[j];
      e += __shfl_xor(e, 1, 64);
      e += __shfl_xor(e, 2, 64);
      e += __shfl_xor(e, 4, 64);
      e += __shfl_xor(e, 8, 64);
      if (l15 == 0) atomicAdd(rs + browbase + j, e);
    }
  }
}

// ---------------------------------------------------------------------------
// Kernel 4: loss = mean(log(rowsum) - tgtlog) per modality
// ---------------------------------------------------------------------------
__global__ void loss_kernel(const float* __restrict__ rowsum,
                            const float* __restrict__ tgtlog,
                            float* __restrict__ out) {
  int t = threadIdx.x;  // 512
  float lr = logf(rowsum[t]) - tgtlog[t];
  float li = logf(rowsum[BATCH + t]) - tgtlog[BATCH + t];
#pragma unroll
  for (int m = 1; m < 64; m <<= 1) { lr += __shfl_xor(lr, m, 64); li += __shfl_xor(li, m, 64); }
  __shared__ float sr[8], si[8];
  if ((t & 63) == 0) { sr[t >> 6] = lr; si[t >> 6] = li; }
  __syncthreads();
  if (t == 0) {
    float a = 0.f, b = 0.f;
#pragma unroll
    for (int i = 0; i < 8; ++i) { a += sr[i]; b += si[i]; }
    out[0] = a * (1.0f / BATCH);
    out[1] = b * (1.0f / BATCH);
  }
}

// ---------------------------------------------------------------------------
// Kernel 5: sequential momentum update chains on the copied banks.
// ---------------------------------------------------------------------------
__global__ void mom_kernel(const int* __restrict__ t_rgb,
                           const int* __restrict__ t_ir,
                           const float* __restrict__ xf,   // [2][512][1024]
                           float* __restrict__ out) {      // out + 2 base
  const int i   = blockIdx.x;
  const int mod = blockIdx.y;
  const int* tg = mod ? t_ir : t_rgb;
  const int y = tg[i];
  for (int j = 0; j < i; ++j)
    if (tg[j] == y) return;          // uniform: another block owns this chain

  const float* x = xf + (size_t)mod * BATCH * DIM;
  float* rowp = out + (size_t)mod * NCLUS * DIM + (size_t)y * DIM;

  const int t = threadIdx.x;  // 256
  float2 r0 = ((const float2*)rowp)[t];
  float2 r1 = ((const float2*)rowp)[t + 256];
  __shared__ float red[4];

  for (int j = i; j < BATCH; ++j) {
    if (tg[j] != y) continue;        // uniform
    const float2* xr = (const float2*)(x + (size_t)j * DIM);
    float2 x0 = xr[t], x1 = xr[t + 256];
    r0.x = 0.9f * r0.x + 0.1f * x0.x;
    r0.y = 0.9f * r0.y + 0.1f * x0.y;
    r1.x = 0.9f * r1.x + 0.1f * x1.x;
    r1.y = 0.9f * r1.y + 0.1f * x1.y;
    float ss = r0.x*r0.x + r0.y*r0.y + r1.x*r1.x + r1.y*r1.y;
#pragma unroll
    for (int m = 1; m < 64; m <<= 1) ss += __shfl_xor(ss, m, 64);
    if ((t & 63) == 0) red[t >> 6] = ss;
    __syncthreads();
    float tot = red[0] + red[1] + red[2] + red[3];
    __syncthreads();
    float inv = 1.0f / sqrtf(tot);
    r0.x *= inv; r0.y *= inv; r1.x *= inv; r1.y *= inv;
  }
  ((float2*)rowp)[t] = r0;
  ((float2*)rowp)[t + 256] = r1;
}

// ---------------------------------------------------------------------------
extern "C" void kernel_launch(void* const* d_in, const int* in_sizes, int n_in,
                              void* d_out, int out_size, void* d_ws, size_t ws_size,
                              hipStream_t stream) {
  (void)in_sizes; (void)n_in; (void)out_size;
  const float* in_rgb = (const float*)d_in[0];
  const float* in_ir  = (const float*)d_in[1];
  const int*   t_rgb  = (const int*)d_in[2];
  const int*   t_ir   = (const int*)d_in[3];
  const float* f_rgb  = (const float*)d_in[4];
  const float* f_ir   = (const float*)d_in[5];
  float* out = (float*)d_out;

  char* ws = (char*)d_ws;
  float*          xf     = (float*)ws;                       // 4 MB  [2][512][1024] f32
  unsigned short* xb     = (unsigned short*)(ws + (4u<<20)); // 2 MB  [2][512][1024] bf16
  float*          rowsum = (float*)(ws + (6u<<20));          // 2048 f32 (rowsum+tgtlog)
  float*          tgtlog = rowsum + 1024;
  unsigned short* fb     = (unsigned short*)(ws + (8u<<20)); // 64 MB [2][16384][1024] bf16
  const int precvt = (ws_size >= ((size_t)72 << 20)) ? 1 : 0;

  nrm_kernel<<<1024, 256, 0, stream>>>(in_rgb, in_ir, xf, xb, rowsum);
  cvtcopy_kernel<<<2048, 256, 0, stream>>>(f_rgb, f_ir, out + 2, fb, precvt);
  if (precvt)
    gemm_lse_kernel<1><<<dim3(128, 8), 256, 0, stream>>>(xb, fb, f_rgb, f_ir,
                                                         t_rgb, t_ir, rowsum, tgtlog);
  else
    gemm_lse_kernel<0><<<dim3(128, 8), 256, 0, stream>>>(xb, fb, f_rgb, f_ir,
                                                         t_rgb, t_ir, rowsum, tgtlog);
  mom_kernel<<<dim3(512, 2), 256, 0, stream>>>(t_rgb, t_ir, xf, out + 2);
  loss_kernel<<<1, 512, 0, stream>>>(rowsum, tgtlog, out);
}